// Round 1
// baseline (389.146 us; speedup 1.0000x reference)
//
#include <hip/hip_runtime.h>
#include <math.h>

#define T_DIM 256
#define B_DIM 256
#define H_DIM 512
#define K_DIM 64

// ---------------------------------------------------------------------------
// Emission GEMM: em[b][t][k] = dot(hiddens[t][b][:], W[k][:]) + bias[k]
// Output layout [B, T, K] so the DP kernel streams contiguous memory per batch.
// 64-row x 64-col tile per block, 256 threads, 4x4 micro-tile, TK=32 chunks.
// LDS tiles stored transposed [kk][row] so compute reads are ds_read_b128.
// ---------------------------------------------------------------------------
__global__ __launch_bounds__(256) void emis_gemm(
    const float* __restrict__ hid,   // [T,B,H]
    const float* __restrict__ W,     // [K,H]
    const float* __restrict__ bias,  // [K]
    float* __restrict__ em)          // [B,T,K]
{
  __shared__ float As[32][64];  // [kk][row]
  __shared__ float Bs[32][64];  // [kk][col]
  const int tid = threadIdx.x;
  const int block_m = blockIdx.x * 64;
  const int tx = tid & 15;   // col group (k)
  const int ty = tid >> 4;   // row group (m)
  float acc[4][4] = {{0.f,0.f,0.f,0.f},{0.f,0.f,0.f,0.f},
                     {0.f,0.f,0.f,0.f},{0.f,0.f,0.f,0.f}};

  for (int h0 = 0; h0 < H_DIM; h0 += 32) {
    // Cooperative load: 64 rows x 32 h for A (hiddens tile) and B (W, all 64 k rows).
    // mapping: q -> r = q>>3 (row), c4 = (q&7)*4 (kk base); float4 along h.
#pragma unroll
    for (int qq = 0; qq < 2; ++qq) {
      const int q = tid + qq * 256;
      const int r = q >> 3;
      const int c4 = (q & 7) << 2;
      const float4 va = *(const float4*)(hid + (size_t)(block_m + r) * H_DIM + h0 + c4);
      As[c4 + 0][r] = va.x; As[c4 + 1][r] = va.y;
      As[c4 + 2][r] = va.z; As[c4 + 3][r] = va.w;
      const float4 vb = *(const float4*)(W + (size_t)r * H_DIM + h0 + c4);
      Bs[c4 + 0][r] = vb.x; Bs[c4 + 1][r] = vb.y;
      Bs[c4 + 2][r] = vb.z; Bs[c4 + 3][r] = vb.w;
    }
    __syncthreads();
#pragma unroll
    for (int kk = 0; kk < 32; ++kk) {
      const float4 a  = *(const float4*)(&As[kk][ty << 2]);
      const float4 bv = *(const float4*)(&Bs[kk][tx << 2]);
      acc[0][0] += a.x * bv.x; acc[0][1] += a.x * bv.y;
      acc[0][2] += a.x * bv.z; acc[0][3] += a.x * bv.w;
      acc[1][0] += a.y * bv.x; acc[1][1] += a.y * bv.y;
      acc[1][2] += a.y * bv.z; acc[1][3] += a.y * bv.w;
      acc[2][0] += a.z * bv.x; acc[2][1] += a.z * bv.y;
      acc[2][2] += a.z * bv.z; acc[2][3] += a.z * bv.w;
      acc[3][0] += a.w * bv.x; acc[3][1] += a.w * bv.y;
      acc[3][2] += a.w * bv.z; acc[3][3] += a.w * bv.w;
    }
    __syncthreads();
  }

  const float4 b4 = *(const float4*)(bias + (tx << 2));
#pragma unroll
  for (int i = 0; i < 4; ++i) {
    const int m = block_m + (ty << 2) + i;   // m = t*B + b (hiddens row order)
    const int t = m >> 8;                    // B_DIM == 256
    const int b = m & 255;
    float4 v;
    v.x = acc[i][0] + b4.x; v.y = acc[i][1] + b4.y;
    v.z = acc[i][2] + b4.z; v.w = acc[i][3] + b4.w;
    *(float4*)(em + ((size_t)b * T_DIM + t) * K_DIM + (tx << 2)) = v;
  }
}

// ---------------------------------------------------------------------------
// CRF forward DP + gold score, one block per batch element.
// alpha_t[j] = logsumexp_i(alpha[i] + T[j,i]) + em_t[j]
//            = M + log( sum_i exp(T[j,i]) * exp(alpha[i]-M) ) + em_t[j]
// with M = max_i alpha[i]  (single max per step; exp(T) precomputed in regs,
// exp(alpha-M) computed once per i, shared across all j via LDS).
// 256 threads: j = tid>>2 (0..63), part = tid&3 -> 16 i's per thread.
// Loops only to lens[b]-1. Next em row prefetched into registers.
// ---------------------------------------------------------------------------
__global__ __launch_bounds__(256) void crf_dp(
    const float* __restrict__ em,     // [B,T,K]
    const int* __restrict__ lens,     // [B]
    const int* __restrict__ tags,     // [T,B]
    const float* __restrict__ trans,  // [K,K]  trans[j*64+i]
    const float* __restrict__ beginT, // [K]
    const float* __restrict__ endT,   // [K]
    float* __restrict__ out)          // [1], pre-zeroed
{
  const int b   = blockIdx.x;
  const int tid = threadIdx.x;
  const int j    = tid >> 2;
  const int part = tid & 3;

  __shared__ float alpha[2][64];
  __shared__ float ealpha[64];
  __shared__ float emRow[64];
  __shared__ float transS[K_DIM * K_DIM];
  __shared__ int   tagsS[T_DIM];
  __shared__ float Msh;

  // expT[u] = exp(trans[j][part*16+u]) cached in registers
  float expT[16];
#pragma unroll
  for (int u = 0; u < 16; ++u)
    expT[u] = __expf(trans[j * K_DIM + part * 16 + u]);

  // transition table into LDS (for the gold-path lookup), coalesced
  for (int q = tid; q < K_DIM * K_DIM; q += 256) transS[q] = trans[q];
  // gold tags for this batch element, all T of them
  tagsS[tid] = tags[tid * B_DIM + b];

  const int len = lens[b];
  const float* emB = em + (size_t)b * T_DIM * K_DIM;

  float eNext = 0.f;
  if (tid < 64) {
    const float e0 = emB[tid];
    emRow[tid] = e0;
    alpha[0][tid] = e0 + beginT[tid];
    eNext = emB[K_DIM + tid];   // row 1 prefetch (T_DIM >= 2)
  }
  __syncthreads();

  float gold = 0.f;
  int prevTag = 0;
  if (tid == 0) {
    prevTag = tagsS[0];
    gold = beginT[prevTag] + emB[prevTag];  // read from global: no race with emRow rewrite
  }

  int cur = 0;
  for (int t = 1; t < len; ++t) {
    // ---- phase A: wave0 computes M, exp(alpha-M); stages em row t; prefetches t+1
    if (tid < 64) {
      const float v = alpha[cur][tid];
      float m = v;
#pragma unroll
      for (int o = 1; o < 64; o <<= 1) m = fmaxf(m, __shfl_xor(m, o));
      ealpha[tid] = __expf(v - m);
      emRow[tid] = eNext;
      if (tid == 0) Msh = m;
      const int tn = (t + 1 < T_DIM) ? (t + 1) : (T_DIM - 1);
      eNext = emB[tn * K_DIM + tid];
    }
    __syncthreads();

    // ---- phase B: s_j = sum_i expT[j,i] * ealpha[i]  (16 fma per thread)
    const float4 e0 = *(const float4*)(&ealpha[part * 16 + 0]);
    const float4 e1 = *(const float4*)(&ealpha[part * 16 + 4]);
    const float4 e2 = *(const float4*)(&ealpha[part * 16 + 8]);
    const float4 e3 = *(const float4*)(&ealpha[part * 16 + 12]);
    float s = 0.f;
    s += expT[0]  * e0.x; s += expT[1]  * e0.y; s += expT[2]  * e0.z; s += expT[3]  * e0.w;
    s += expT[4]  * e1.x; s += expT[5]  * e1.y; s += expT[6]  * e1.z; s += expT[7]  * e1.w;
    s += expT[8]  * e2.x; s += expT[9]  * e2.y; s += expT[10] * e2.z; s += expT[11] * e2.w;
    s += expT[12] * e3.x; s += expT[13] * e3.y; s += expT[14] * e3.z; s += expT[15] * e3.w;
    s += __shfl_xor(s, 1);
    s += __shfl_xor(s, 2);
    if (part == 0) alpha[cur ^ 1][j] = Msh + __logf(s) + emRow[j];
    if (tid == 0) {
      const int tg = tagsS[t];
      gold += transS[tg * K_DIM + prevTag] + emRow[tg];
      prevTag = tg;
    }
    __syncthreads();
    cur ^= 1;
  }

  // ---- final: forward = logsumexp(alpha_{len-1} + end); gold += end[lastTag]
  if (tid < 64) {
    const float v = alpha[cur][tid] + endT[tid];
    float m = v;
#pragma unroll
    for (int o = 1; o < 64; o <<= 1) m = fmaxf(m, __shfl_xor(m, o));
    float s = __expf(v - m);
#pragma unroll
    for (int o = 1; o < 64; o <<= 1) s += __shfl_xor(s, o);
    if (tid == 0) {
      const float fwd = m + __logf(s);
      const float g = gold + endT[prevTag];
      atomicAdd(out, fwd - g);
    }
  }
}

// ---------------------------------------------------------------------------
extern "C" void kernel_launch(void* const* d_in, const int* in_sizes, int n_in,
                              void* d_out, int out_size, void* d_ws, size_t ws_size,
                              hipStream_t stream) {
  const float* hiddens = (const float*)d_in[0];  // [T,B,H]
  const int*   lens    = (const int*)  d_in[1];  // [B]
  const int*   tags    = (const int*)  d_in[2];  // [T,B]
  const float* W       = (const float*)d_in[3];  // [K,H]
  const float* bias    = (const float*)d_in[4];  // [K]
  const float* beginT  = (const float*)d_in[5];  // [K]
  const float* trans   = (const float*)d_in[6];  // [K,K]
  const float* endT    = (const float*)d_in[7];  // [K]

  float* em  = (float*)d_ws;   // [B,T,K] fp32 = 16.8 MB
  float* out = (float*)d_out;  // scalar

  hipMemsetAsync(out, 0, sizeof(float), stream);
  emis_gemm<<<(T_DIM * B_DIM) / 64, 256, 0, stream>>>(hiddens, W, bias, em);
  crf_dp<<<B_DIM, 256, 0, stream>>>(em, lens, tags, trans, beginT, endT, out);
}

// Round 2
// 375.080 us; speedup vs baseline: 1.0375x; 1.0375x over previous
//
#include <hip/hip_runtime.h>
#include <hip/hip_bf16.h>
#include <math.h>

#define T_DIM 256
#define B_DIM 256
#define H_DIM 512
#define K_DIM 64

typedef __attribute__((ext_vector_type(8))) short bfrag_t;  // 8 bf16 (4 VGPRs)
typedef __attribute__((ext_vector_type(4))) float f4_t;     // 4 fp32

// Convert 8 fp32 -> 8 bf16 (RNE) packed for an MFMA A/B fragment.
__device__ inline bfrag_t pack8(float4 a, float4 b) {
  union { bfrag_t v; __hip_bfloat162 h[4]; } u;
  u.h[0] = __float22bfloat162_rn(float2{a.x, a.y});
  u.h[1] = __float22bfloat162_rn(float2{a.z, a.w});
  u.h[2] = __float22bfloat162_rn(float2{b.x, b.y});
  u.h[3] = __float22bfloat162_rn(float2{b.z, b.w});
  return u.v;
}

// ---------------------------------------------------------------------------
// Emission GEMM via bf16 MFMA: em[b][t][n] = hid[m=t*256+b][:]·W[n][:] + bias[n]
// Block = 256 thr = 4 waves; block tile 128 (m) x 64 (n); wave w -> n-cols
// [16w,16w+16). No LDS: A-frags straight from global (16 rows x 128B lines),
// B-frags (W rows, bf16) preloaded into 64 VGPRs per lane.
// MFMA layouts (guide §3, HW-verified): A reg r = A[lane&15][quad*8+r],
// B reg r = B[quad*8+r][lane&15], D reg r = D[quad*4+r][lane&15].
// ---------------------------------------------------------------------------
__global__ __launch_bounds__(256) void emis_gemm_mfma(
    const float* __restrict__ hid,   // [T*B, H]
    const float* __restrict__ W,     // [K,H]
    const float* __restrict__ bias,  // [K]
    float* __restrict__ em)          // [B,T,K]
{
  const int tid  = threadIdx.x;
  const int wave = tid >> 6;
  const int lane = tid & 63;
  const int l16  = lane & 15;
  const int quad = lane >> 4;

  // ---- preload B-frags: W row (16*wave + l16), all 16 k-chunks of 32
  bfrag_t bfrag[16];
  {
    const float* wr = W + (size_t)(wave * 16 + l16) * H_DIM + quad * 8;
#pragma unroll
    for (int kc = 0; kc < 16; ++kc) {
      const float4 w0 = *(const float4*)(wr + kc * 32);
      const float4 w1 = *(const float4*)(wr + kc * 32 + 4);
      bfrag[kc] = pack8(w0, w1);
    }
  }

  const int m0 = blockIdx.x * 128;
  f4_t acc[8];
#pragma unroll
  for (int mt = 0; mt < 8; ++mt) acc[mt] = (f4_t){0.f, 0.f, 0.f, 0.f};

  const float* abase = hid + (size_t)(m0 + l16) * H_DIM + quad * 8;
#pragma unroll
  for (int kc = 0; kc < 16; ++kc) {
#pragma unroll
    for (int mt = 0; mt < 8; ++mt) {
      const float* ap = abase + (size_t)mt * 16 * H_DIM + kc * 32;
      const float4 a0 = *(const float4*)(ap);
      const float4 a1 = *(const float4*)(ap + 4);
      const bfrag_t af = pack8(a0, a1);
      acc[mt] = __builtin_amdgcn_mfma_f32_16x16x32_bf16(af, bfrag[kc], acc[mt], 0, 0, 0);
    }
  }

  const float bn = bias[wave * 16 + l16];
  const int   col = wave * 16 + l16;
#pragma unroll
  for (int mt = 0; mt < 8; ++mt) {
#pragma unroll
    for (int r = 0; r < 4; ++r) {
      const int m = m0 + mt * 16 + quad * 4 + r;   // m = t*256 + b
      const int t = m >> 8;
      const int b = m & 255;
      em[((size_t)b * T_DIM + t) * K_DIM + col] = acc[mt][r] + bn;
    }
  }
}

// ---------------------------------------------------------------------------
// CRF DP, wave-synchronous: 1 wave per batch element, lane = tag j.
// alpha_j' = M + log( sum_i exp(T[j,i]) * exp(alpha_i - M) ) + em_t[j],
// M = alpha_0 (any finite M is exact for logsumexp; spread << fp32 exp range).
// exp(T[j,:]) cached in 64 VGPRs/lane; broadcast of e_i via __shfl (readlane).
// NO barriers, NO LDS -> em prefetch stays in flight across steps.
// Gold path score computed in parallel over t (4 strided chunks per lane).
// ---------------------------------------------------------------------------
__global__ __launch_bounds__(64) void crf_dp2(
    const float* __restrict__ em,     // [B,T,K]
    const int* __restrict__ lens,     // [B]
    const int* __restrict__ tags,     // [T,B]
    const float* __restrict__ trans,  // [K,K]  trans[j*64+i]
    const float* __restrict__ beginT, // [K]
    const float* __restrict__ endT,   // [K]
    float* __restrict__ out)          // [1], pre-zeroed
{
  const int b    = blockIdx.x;
  const int lane = threadIdx.x;   // tag index j (and i for broadcasts)

  // expT[i] = exp(trans[lane][i])
  float expT[64];
  {
    const float* trow = trans + (size_t)lane * K_DIM;
#pragma unroll
    for (int i = 0; i < 64; i += 4) {
      const float4 v = *(const float4*)(trow + i);
      expT[i + 0] = __expf(v.x);
      expT[i + 1] = __expf(v.y);
      expT[i + 2] = __expf(v.z);
      expT[i + 3] = __expf(v.w);
    }
  }

  const int len = lens[b];
  const float* emB = em + (size_t)b * T_DIM * K_DIM;

  float alpha = emB[lane] + beginT[lane];
  float eNext = emB[K_DIM + lane];   // row 1 prefetch (row always exists)

  for (int t = 1; t < len; ++t) {
    const float M = __shfl(alpha, 0);
    const float e = __expf(alpha - M);
    const float emj = eNext;
    const int tn = (t + 1 < T_DIM) ? (t + 1) : (T_DIM - 1);
    eNext = emB[(size_t)tn * K_DIM + lane];   // prefetch next row

    float s0 = 0.f, s1 = 0.f, s2 = 0.f, s3 = 0.f;
#pragma unroll
    for (int i = 0; i < 64; i += 4) {
      s0 += expT[i + 0] * __shfl(e, i + 0);
      s1 += expT[i + 1] * __shfl(e, i + 1);
      s2 += expT[i + 2] * __shfl(e, i + 2);
      s3 += expT[i + 3] * __shfl(e, i + 3);
    }
    alpha = M + __logf((s0 + s1) + (s2 + s3)) + emj;
  }

  // ---- forward score: logsumexp(alpha + endT)
  float v = alpha + endT[lane];
  float m = v;
#pragma unroll
  for (int o = 1; o < 64; o <<= 1) m = fmaxf(m, __shfl_xor(m, o));
  float se = __expf(v - m);
#pragma unroll
  for (int o = 1; o < 64; o <<= 1) se += __shfl_xor(se, o);

  // ---- gold path score, parallel over t: lane handles t = lane + 64c
  int tg[4];
#pragma unroll
  for (int c = 0; c < 4; ++c)
    tg[c] = tags[(size_t)(lane + 64 * c) * B_DIM + b];

  float g = 0.f;
#pragma unroll
  for (int c = 0; c < 4; ++c) {
    int pv = __shfl_up(tg[c], 1);                       // tag at t-1 (same chunk)
    const int bnd = (c > 0) ? __shfl(tg[c - 1], 63) : 0; // chunk-boundary prev
    if (lane == 0) pv = bnd;
    const int t = lane + 64 * c;
    if (t < len) {
      float contrib = emB[(size_t)t * K_DIM + tg[c]];
      contrib += (t == 0) ? beginT[tg[c]] : trans[(size_t)tg[c] * K_DIM + pv];
      if (t == len - 1) contrib += endT[tg[c]];
      g += contrib;
    }
  }
#pragma unroll
  for (int o = 1; o < 64; o <<= 1) g += __shfl_xor(g, o);

  if (lane == 0) {
    const float fwd = m + __logf(se);
    atomicAdd(out, fwd - g);
  }
}

// ---------------------------------------------------------------------------
extern "C" void kernel_launch(void* const* d_in, const int* in_sizes, int n_in,
                              void* d_out, int out_size, void* d_ws, size_t ws_size,
                              hipStream_t stream) {
  const float* hiddens = (const float*)d_in[0];  // [T,B,H]
  const int*   lens    = (const int*)  d_in[1];  // [B]
  const int*   tags    = (const int*)  d_in[2];  // [T,B]
  const float* W       = (const float*)d_in[3];  // [K,H]
  const float* bias    = (const float*)d_in[4];  // [K]
  const float* beginT  = (const float*)d_in[5];  // [K]
  const float* trans   = (const float*)d_in[6];  // [K,K]
  const float* endT    = (const float*)d_in[7];  // [K]

  float* em  = (float*)d_ws;   // [B,T,K] fp32 = 16.8 MB
  float* out = (float*)d_out;  // scalar

  hipMemsetAsync(out, 0, sizeof(float), stream);
  emis_gemm_mfma<<<(T_DIM * B_DIM) / 128, 256, 0, stream>>>(hiddens, W, bias, em);
  crf_dp2<<<B_DIM, 64, 0, stream>>>(em, lens, tags, trans, beginT, endT, out);
}

// Round 3
// 337.210 us; speedup vs baseline: 1.1540x; 1.1123x over previous
//
#include <hip/hip_runtime.h>
#include <hip/hip_bf16.h>
#include <math.h>

#define T_DIM 256
#define B_DIM 256
#define H_DIM 512
#define K_DIM 64

typedef __attribute__((ext_vector_type(8))) short bfrag_t;  // 8 bf16 (4 VGPRs)
typedef __attribute__((ext_vector_type(4))) float f4_t;     // 4 fp32

// Pack 8 fp32 -> 8 bf16 (RNE) for an MFMA A/B fragment.
__device__ inline bfrag_t pack8(float4 a, float4 b) {
  union { bfrag_t v; __hip_bfloat162 h[4]; } u;
  u.h[0] = __float22bfloat162_rn(float2{a.x, a.y});
  u.h[1] = __float22bfloat162_rn(float2{a.z, a.w});
  u.h[2] = __float22bfloat162_rn(float2{b.x, b.y});
  u.h[3] = __float22bfloat162_rn(float2{b.z, b.w});
  return u.v;
}

// Async global->LDS, 16 B per lane. LDS dst is wave-uniform base + lane*16.
__device__ inline void async_ld16(const float* g, float* l) {
  __builtin_amdgcn_global_load_lds(
      (const __attribute__((address_space(1))) void*)g,
      (__attribute__((address_space(3))) void*)l, 16, 0, 0);
}

// ---------------------------------------------------------------------------
// Emission: eemP = exp(hid·W^T + bias), written in the DP kernel's per-lane
// permuted layout:
//   idx(t,b,j) = (((b>>4)*256 + t)*64 + ((j>>2)&3)*16 + (b&15))*16 + (j>>4)*4 + (j&3)
// Block: 256 thr (4 waves), tile M=128 x N=64, K-loop BK=64, LDS double-buffer
// staged by global_load_lds with an XOR chunk swizzle (16-B granules):
//   LDS (row, c) holds global chunk c ^ (row&3)  -> readers use c = G ^ (l16&3),
// giving uniform bank load (8 lanes per 4-bank group = minimum cycles).
// ---------------------------------------------------------------------------
__global__ __launch_bounds__(256) void emis_gemm3(
    const float* __restrict__ hid,   // [T*B, H]
    const float* __restrict__ W,     // [K,H]
    const float* __restrict__ bias,  // [K]
    float* __restrict__ emP)
{
  __shared__ float As[2][128 * 64];  // 2 x 32 KB
  const int tid  = threadIdx.x;
  const int wv   = tid >> 6;
  const int lane = tid & 63;
  const int l16  = lane & 15;
  const int quad = lane >> 4;
  const int m0   = blockIdx.x * 128;

  // B-frags: W row (16*wv + l16), 16 k-chunks of 32. B[k=quad*8+r][n=l16].
  bfrag_t bw[16];
  {
    const float* wr = W + (size_t)(wv * 16 + l16) * H_DIM + quad * 8;
#pragma unroll
    for (int kc = 0; kc < 16; ++kc)
      bw[kc] = pack8(*(const float4*)(wr + kc * 32), *(const float4*)(wr + kc * 32 + 4));
  }

  // Staging: wave wv covers rows [wv*32, wv*32+32), 8 instrs x (4 rows x 64 f).
  const int srow   = wv * 32 + (lane >> 4);              // + inst*4
  const int schunk = (lane & 15) ^ ((lane >> 4) & 3);    // XOR swizzle on global side

  f4_t acc[8];
#pragma unroll
  for (int mt = 0; mt < 8; ++mt) acc[mt] = (f4_t){0.f, 0.f, 0.f, 0.f};

  // stage iter 0
#pragma unroll
  for (int inst = 0; inst < 8; ++inst)
    async_ld16(hid + (size_t)(m0 + srow + inst * 4) * H_DIM + 0 * 64 + schunk * 4,
               &As[0][(wv * 32 + inst * 4) * 64]);
  __syncthreads();

  int buf = 0;
  for (int it = 0; it < 8; ++it) {
    if (it < 7) {
#pragma unroll
      for (int inst = 0; inst < 8; ++inst)
        async_ld16(hid + (size_t)(m0 + srow + inst * 4) * H_DIM + (it + 1) * 64 + schunk * 4,
                   &As[buf ^ 1][(wv * 32 + inst * 4) * 64]);
    }
#pragma unroll
    for (int kc2 = 0; kc2 < 2; ++kc2) {
#pragma unroll
      for (int mt = 0; mt < 8; ++mt) {
        const int row = mt * 16 + l16;
        const int c0  = (kc2 * 8 + quad * 2 + 0) ^ (l16 & 3);
        const int c1  = (kc2 * 8 + quad * 2 + 1) ^ (l16 & 3);
        const float4 a0 = *(const float4*)(&As[buf][row * 64 + c0 * 4]);
        const float4 a1 = *(const float4*)(&As[buf][row * 64 + c1 * 4]);
        acc[mt] = __builtin_amdgcn_mfma_f32_16x16x32_bf16(pack8(a0, a1), bw[it * 2 + kc2],
                                                          acc[mt], 0, 0, 0);
      }
    }
    __syncthreads();
    buf ^= 1;
  }

  // Epilogue: eem = exp(acc + bias), store in permuted layout.
  const float bn = bias[wv * 16 + l16];
#pragma unroll
  for (int mt = 0; mt < 8; ++mt) {
#pragma unroll
    for (int r = 0; r < 4; ++r) {
      const int m = m0 + mt * 16 + quad * 4 + r;  // m = t*256 + b
      const int t = m >> 8;
      const int b = m & 255;
      const float v = __expf(acc[mt][r] + bn);
      emP[((((size_t)(b >> 4) * 256 + t) * 64 + (l16 >> 2) * 16 + (b & 15)) << 4)
          + wv * 4 + (l16 & 3)] = v;
    }
  }
}

// ---------------------------------------------------------------------------
// CRF DP in the LINEAR domain: x_t = (E · x_{t-1}) ⊙ eem_t, E = exp(trans),
// with periodic exact power-of-2 rescale (frexp/ldexp, integer exponent Lint).
// One wave handles 16 batch columns via mfma_16x16x32_bf16:
//   D[j=quad*4+r (+16*jt)][n=lane&15=batch]  —  B-frag of the next step is a
// plain bf16 cvt of D because E's columns are PRE-PERMUTED to match (E const).
// No exp/log/LDS/barriers in the 256-step serial chain.
// ---------------------------------------------------------------------------
__global__ __launch_bounds__(64) void crf_dp3(
    const float* __restrict__ emP,
    const int* __restrict__ lens,
    const int* __restrict__ tags,
    const float* __restrict__ trans,
    const float* __restrict__ beginT,
    const float* __restrict__ endT,
    float* __restrict__ out)
{
  const int g    = blockIdx.x;
  const int lane = threadIdx.x;
  const int n    = lane & 15;
  const int q    = lane >> 4;
  const int b    = g * 16 + n;

  // E A-frags, pre-permuted: aE[jt*2+kt] reg r holds
  //   E[jt*16 + n][ (2*kt + (r>>2))*16 + q*4 + (r&3) ]   (bf16 of exp(trans))
  bfrag_t aE[8];
#pragma unroll
  for (int jt = 0; jt < 4; ++jt) {
#pragma unroll
    for (int kt = 0; kt < 2; ++kt) {
      union { bfrag_t v; __hip_bfloat16 h[8]; } u;
#pragma unroll
      for (int r = 0; r < 8; ++r) {
        const int i = (2 * kt + (r >> 2)) * 16 + q * 4 + (r & 3);
        u.h[r] = __float2bfloat16(__expf(trans[(jt * 16 + n) * K_DIM + i]));
      }
      aE[jt * 2 + kt] = u.v;
    }
  }

  const int len = lens[b];
  const int cap = len - 1;
  const float* base = emP + (((size_t)g * 256) * 64 + lane) * 16;

#define LOADW(dst, t) { \
    const float4 _a = *(const float4*)(base + (size_t)(t) * 1024 + 0); \
    const float4 _b = *(const float4*)(base + (size_t)(t) * 1024 + 4); \
    const float4 _c = *(const float4*)(base + (size_t)(t) * 1024 + 8); \
    const float4 _d = *(const float4*)(base + (size_t)(t) * 1024 + 12); \
    dst[0]=_a.x; dst[1]=_a.y; dst[2]=_a.z; dst[3]=_a.w; \
    dst[4]=_b.x; dst[5]=_b.y; dst[6]=_b.z; dst[7]=_b.w; \
    dst[8]=_c.x; dst[9]=_c.y; dst[10]=_c.z; dst[11]=_c.w; \
    dst[12]=_d.x; dst[13]=_d.y; dst[14]=_d.z; dst[15]=_d.w; }

  float w0buf[16], w1[16], w2[16];
  LOADW(w0buf, 0);
  LOADW(w1, 1);
  LOADW(w2, 2);

  float y[16], snap[16];
  int Lint = 0, Lsnap = 0;

  // t = 0: x0 = eem_0 * exp(beginT)
#pragma unroll
  for (int k = 0; k < 16; ++k) {
    const int j = (k >> 2) * 16 + q * 4 + (k & 3);
    y[k] = w0buf[k] * __expf(beginT[j]);
    snap[k] = (cap == 0) ? y[k] : 0.0f;
  }

#define RESCALE() { \
    float _mx = y[0]; \
    _Pragma("unroll") for (int k = 1; k < 16; ++k) _mx = fmaxf(_mx, y[k]); \
    _mx = fmaxf(_mx, __shfl_xor(_mx, 16)); \
    _mx = fmaxf(_mx, __shfl_xor(_mx, 32)); \
    int _e; (void)frexpf(_mx, &_e); \
    Lint += _e; \
    _Pragma("unroll") for (int k = 0; k < 16; ++k) y[k] = ldexpf(y[k], -_e); }

  RESCALE();

  bfrag_t bf0, bf1;
#define BUILDB() { \
    union { bfrag_t v; __hip_bfloat162 h[4]; } _u0, _u1; \
    _u0.h[0] = __float22bfloat162_rn(float2{y[0], y[1]}); \
    _u0.h[1] = __float22bfloat162_rn(float2{y[2], y[3]}); \
    _u0.h[2] = __float22bfloat162_rn(float2{y[4], y[5]}); \
    _u0.h[3] = __float22bfloat162_rn(float2{y[6], y[7]}); \
    _u1.h[0] = __float22bfloat162_rn(float2{y[8], y[9]}); \
    _u1.h[1] = __float22bfloat162_rn(float2{y[10], y[11]}); \
    _u1.h[2] = __float22bfloat162_rn(float2{y[12], y[13]}); \
    _u1.h[3] = __float22bfloat162_rn(float2{y[14], y[15]}); \
    bf0 = _u0.v; bf1 = _u1.v; }

  BUILDB();

  const f4_t zro = (f4_t){0.f, 0.f, 0.f, 0.f};

#define STEP(T, W) { \
    f4_t _a0 = __builtin_amdgcn_mfma_f32_16x16x32_bf16(aE[0], bf0, zro, 0, 0, 0); \
    f4_t _a1 = __builtin_amdgcn_mfma_f32_16x16x32_bf16(aE[2], bf0, zro, 0, 0, 0); \
    f4_t _a2 = __builtin_amdgcn_mfma_f32_16x16x32_bf16(aE[4], bf0, zro, 0, 0, 0); \
    f4_t _a3 = __builtin_amdgcn_mfma_f32_16x16x32_bf16(aE[6], bf0, zro, 0, 0, 0); \
    _a0 = __builtin_amdgcn_mfma_f32_16x16x32_bf16(aE[1], bf1, _a0, 0, 0, 0); \
    _a1 = __builtin_amdgcn_mfma_f32_16x16x32_bf16(aE[3], bf1, _a1, 0, 0, 0); \
    _a2 = __builtin_amdgcn_mfma_f32_16x16x32_bf16(aE[5], bf1, _a2, 0, 0, 0); \
    _a3 = __builtin_amdgcn_mfma_f32_16x16x32_bf16(aE[7], bf1, _a3, 0, 0, 0); \
    _Pragma("unroll") for (int r = 0; r < 4; ++r) { \
      y[r]      = _a0[r] * W[r]; \
      y[4 + r]  = _a1[r] * W[4 + r]; \
      y[8 + r]  = _a2[r] * W[8 + r]; \
      y[12 + r] = _a3[r] * W[12 + r]; } \
    const bool _hit = ((T) == cap); \
    _Pragma("unroll") for (int k = 0; k < 16; ++k) snap[k] = _hit ? y[k] : snap[k]; \
    Lsnap = _hit ? Lint : Lsnap; \
    if (((T) & 3) == 3) { RESCALE(); } \
    BUILDB(); }

  int t = 1;
  for (; t + 1 < T_DIM; t += 2) {
    STEP(t, w1);
    { const int tp = (t + 2 < T_DIM) ? t + 2 : T_DIM - 1; LOADW(w1, tp); }
    STEP(t + 1, w2);
    { const int tp = (t + 3 < T_DIM) ? t + 3 : T_DIM - 1; LOADW(w2, tp); }
  }
  STEP(t, w1);  // t = 255

  // forward score: log( sum_j snap_j * exp(endT_j) ) + Lsnap*ln2
  float dot = 0.f;
#pragma unroll
  for (int k = 0; k < 16; ++k) {
    const int j = (k >> 2) * 16 + q * 4 + (k & 3);
    dot += snap[k] * __expf(endT[j]);
  }
  dot += __shfl_xor(dot, 16);
  dot += __shfl_xor(dot, 32);
  const float fwd = __logf(dot) + (float)Lsnap * 0.69314718055994531f;

  // gold path score: lane (q,n) covers t = q + 4c for its column b
  float gsum = 0.f;
  for (int c = 0; c < 64; ++c) {
    const int tt = q + 4 * c;
    if (tt < len) {
      const int tg = tags[(size_t)tt * B_DIM + b];
      float v = __logf(emP[((((size_t)g * 256 + tt) * 64 + ((tg >> 2) & 3) * 16 + n) << 4)
                           + (tg >> 4) * 4 + (tg & 3)]);
      if (tt == 0) v += beginT[tg];
      else         v += trans[(size_t)tg * K_DIM + tags[(size_t)(tt - 1) * B_DIM + b]];
      if (tt == cap) v += endT[tg];
      gsum += v;
    }
  }
  gsum += __shfl_xor(gsum, 16);
  gsum += __shfl_xor(gsum, 32);

  float res = 0.25f * (fwd - gsum);
#pragma unroll
  for (int o = 1; o < 64; o <<= 1) res += __shfl_xor(res, o);
  if (lane == 0) atomicAdd(out, res);
}

// ---------------------------------------------------------------------------
extern "C" void kernel_launch(void* const* d_in, const int* in_sizes, int n_in,
                              void* d_out, int out_size, void* d_ws, size_t ws_size,
                              hipStream_t stream) {
  const float* hiddens = (const float*)d_in[0];  // [T,B,H]
  const int*   lens    = (const int*)  d_in[1];  // [B]
  const int*   tags    = (const int*)  d_in[2];  // [T,B]
  const float* W       = (const float*)d_in[3];  // [K,H]
  const float* bias    = (const float*)d_in[4];  // [K]
  const float* beginT  = (const float*)d_in[5];  // [K]
  const float* trans   = (const float*)d_in[6];  // [K,K]
  const float* endT    = (const float*)d_in[7];  // [K]

  float* emP = (float*)d_ws;   // 16*256*64*16 fp32 = 16.8 MB
  float* out = (float*)d_out;

  hipMemsetAsync(out, 0, sizeof(float), stream);
  emis_gemm3<<<(T_DIM * B_DIM) / 128, 256, 0, stream>>>(hiddens, W, bias, emP);
  crf_dp3<<<16, 64, 0, stream>>>(emP, lens, tags, trans, beginT, endT, out);
}

// Round 4
// 279.256 us; speedup vs baseline: 1.3935x; 1.2075x over previous
//
#include <hip/hip_runtime.h>
#include <hip/hip_bf16.h>
#include <math.h>

#define T_DIM 256
#define B_DIM 256
#define H_DIM 512
#define K_DIM 64
#define LN2F 0.69314718055994531f

typedef __attribute__((ext_vector_type(8))) short bfrag_t;  // 8 bf16 (4 VGPRs)
typedef __attribute__((ext_vector_type(4))) float f4_t;     // 4 fp32

// Pack 8 fp32 -> 8 bf16 (RNE) for an MFMA A/B fragment.
__device__ inline bfrag_t pack8(float4 a, float4 b) {
  union { bfrag_t v; __hip_bfloat162 h[4]; } u;
  u.h[0] = __float22bfloat162_rn(float2{a.x, a.y});
  u.h[1] = __float22bfloat162_rn(float2{a.z, a.w});
  u.h[2] = __float22bfloat162_rn(float2{b.x, b.y});
  u.h[3] = __float22bfloat162_rn(float2{b.z, b.w});
  return u.v;
}

// Async global->LDS, 16 B per lane. LDS dst is wave-uniform base + lane*16.
__device__ inline void async_ld16(const float* g, float* l) {
  __builtin_amdgcn_global_load_lds(
      (const __attribute__((address_space(1))) void*)g,
      (__attribute__((address_space(3))) void*)l, 16, 0, 0);
}

// ---------------------------------------------------------------------------
// Emission: eemP = exp(hid·W^T + bias) in the DP kernel's per-lane permuted
// layout (unchanged from round 3 — passed absmax 0.0).
// ---------------------------------------------------------------------------
__global__ __launch_bounds__(256) void emis_gemm3(
    const float* __restrict__ hid,   // [T*B, H]
    const float* __restrict__ W,     // [K,H]
    const float* __restrict__ bias,  // [K]
    float* __restrict__ emP)
{
  __shared__ float As[2][128 * 64];  // 2 x 32 KB
  const int tid  = threadIdx.x;
  const int wv   = tid >> 6;
  const int lane = tid & 63;
  const int l16  = lane & 15;
  const int quad = lane >> 4;
  const int m0   = blockIdx.x * 128;

  bfrag_t bw[16];
  {
    const float* wr = W + (size_t)(wv * 16 + l16) * H_DIM + quad * 8;
#pragma unroll
    for (int kc = 0; kc < 16; ++kc)
      bw[kc] = pack8(*(const float4*)(wr + kc * 32), *(const float4*)(wr + kc * 32 + 4));
  }

  const int srow   = wv * 32 + (lane >> 4);
  const int schunk = (lane & 15) ^ ((lane >> 4) & 3);

  f4_t acc[8];
#pragma unroll
  for (int mt = 0; mt < 8; ++mt) acc[mt] = (f4_t){0.f, 0.f, 0.f, 0.f};

#pragma unroll
  for (int inst = 0; inst < 8; ++inst)
    async_ld16(hid + (size_t)(m0 + srow + inst * 4) * H_DIM + 0 * 64 + schunk * 4,
               &As[0][(wv * 32 + inst * 4) * 64]);
  __syncthreads();

  int buf = 0;
  for (int it = 0; it < 8; ++it) {
    if (it < 7) {
#pragma unroll
      for (int inst = 0; inst < 8; ++inst)
        async_ld16(hid + (size_t)(m0 + srow + inst * 4) * H_DIM + (it + 1) * 64 + schunk * 4,
                   &As[buf ^ 1][(wv * 32 + inst * 4) * 64]);
    }
#pragma unroll
    for (int kc2 = 0; kc2 < 2; ++kc2) {
#pragma unroll
      for (int mt = 0; mt < 8; ++mt) {
        const int row = mt * 16 + l16;
        const int c0  = (kc2 * 8 + quad * 2 + 0) ^ (l16 & 3);
        const int c1  = (kc2 * 8 + quad * 2 + 1) ^ (l16 & 3);
        const float4 a0 = *(const float4*)(&As[buf][row * 64 + c0 * 4]);
        const float4 a1 = *(const float4*)(&As[buf][row * 64 + c1 * 4]);
        acc[mt] = __builtin_amdgcn_mfma_f32_16x16x32_bf16(pack8(a0, a1), bw[it * 2 + kc2],
                                                          acc[mt], 0, 0, 0);
      }
    }
    __syncthreads();
    buf ^= 1;
  }

  const float bn = bias[wv * 16 + l16];
#pragma unroll
  for (int mt = 0; mt < 8; ++mt) {
#pragma unroll
    for (int r = 0; r < 4; ++r) {
      const int m = m0 + mt * 16 + quad * 4 + r;  // m = t*256 + b
      const int t = m >> 8;
      const int b = m & 255;
      const float v = __expf(acc[mt][r] + bn);
      emP[((((size_t)(b >> 4) * 256 + t) * 64 + (l16 >> 2) * 16 + (b & 15)) << 4)
          + wv * 4 + (l16 & 3)] = v;
    }
  }
}

// ---------------------------------------------------------------------------
// CRF DP, forward/backward meet-in-the-middle. Block = 2 waves, 16 batch cols.
//  wave 0: x_t = (E x_{t-1}) ⊙ e_t  for t = 0..127  (+ snap at cap<=127)
//  wave 1: u_{t-1} = E^T (u_t ⊙ e_t) for t = 255..128, injecting u=eend at
//          t==cap (columns stay exactly 0 until injected -> scale Lu correct)
//  combine: cap>=128 -> fwd = log(x_127·u_127) + (Lx+Lu)ln2; else snap path.
// Per-column power-of-2 rescale every 4 steps (frexp/ldexp, exact).
// 4-deep register prefetch ring for the emission stream.
// ---------------------------------------------------------------------------
__global__ __launch_bounds__(128) void crf_dp4(
    const float* __restrict__ emP,
    const int* __restrict__ lens,
    const int* __restrict__ tags,
    const float* __restrict__ trans,
    const float* __restrict__ beginT,
    const float* __restrict__ endT,
    float* __restrict__ out)
{
  const int g    = blockIdx.x;
  const int tid  = threadIdx.x;
  const int wv   = tid >> 6;     // 0 = forward, 1 = backward
  const int lane = tid & 63;
  const int n    = lane & 15;
  const int q    = lane >> 4;
  const int b    = g * 16 + n;

  __shared__ float xs[64 * 16];  // x_127 per fwd-lane
  __shared__ int   Lxs[64];
  __shared__ float s0d[16];      // snap·eend per column
  __shared__ int   Ls0[16];
  __shared__ float gpart;        // wave0 gold partial

  const int len = lens[b];
  const int cap = len - 1;
  const float* base = emP + (((size_t)g * 256) * 64 + lane) * 16;

  float eend[16];
#pragma unroll
  for (int k = 0; k < 16; ++k)
    eend[k] = __expf(endT[(k >> 2) * 16 + q * 4 + (k & 3)]);

  float y[16];
  int Lint = 0;
  bfrag_t bf0, bf1;
  float wA[16], wB[16], wC[16], wD[16];
  float g0 = 0.f;   // per-lane gold partial (this wave's t-range)

#define LOADW(dst, t) { \
    const float4 _a = *(const float4*)(base + (size_t)(t) * 1024 + 0); \
    const float4 _b = *(const float4*)(base + (size_t)(t) * 1024 + 4); \
    const float4 _c = *(const float4*)(base + (size_t)(t) * 1024 + 8); \
    const float4 _d = *(const float4*)(base + (size_t)(t) * 1024 + 12); \
    dst[0]=_a.x; dst[1]=_a.y; dst[2]=_a.z; dst[3]=_a.w; \
    dst[4]=_b.x; dst[5]=_b.y; dst[6]=_b.z; dst[7]=_b.w; \
    dst[8]=_c.x; dst[9]=_c.y; dst[10]=_c.z; dst[11]=_c.w; \
    dst[12]=_d.x; dst[13]=_d.y; dst[14]=_d.z; dst[15]=_d.w; }

#define RESCALE() { \
    float _mx = y[0]; \
    _Pragma("unroll") for (int k = 1; k < 16; ++k) _mx = fmaxf(_mx, y[k]); \
    _mx = fmaxf(_mx, __shfl_xor(_mx, 16)); \
    _mx = fmaxf(_mx, __shfl_xor(_mx, 32)); \
    int _e; (void)frexpf(_mx, &_e); \
    Lint += _e; \
    _Pragma("unroll") for (int k = 0; k < 16; ++k) y[k] = ldexpf(y[k], -_e); }

#define BUILDBV(S) { \
    union { bfrag_t v; __hip_bfloat162 h[4]; } _u0, _u1; \
    _u0.h[0] = __float22bfloat162_rn(float2{S[0], S[1]}); \
    _u0.h[1] = __float22bfloat162_rn(float2{S[2], S[3]}); \
    _u0.h[2] = __float22bfloat162_rn(float2{S[4], S[5]}); \
    _u0.h[3] = __float22bfloat162_rn(float2{S[6], S[7]}); \
    _u1.h[0] = __float22bfloat162_rn(float2{S[8], S[9]}); \
    _u1.h[1] = __float22bfloat162_rn(float2{S[10], S[11]}); \
    _u1.h[2] = __float22bfloat162_rn(float2{S[12], S[13]}); \
    _u1.h[3] = __float22bfloat162_rn(float2{S[14], S[15]}); \
    bf0 = _u0.v; bf1 = _u1.v; }

  const f4_t zro = (f4_t){0.f, 0.f, 0.f, 0.f};

#define EMPIDX(tt, tg) (((((size_t)g * 256 + (tt)) * 64 + (((tg) >> 2) & 3) * 16 + n) << 4) \
                        + ((tg) >> 4) * 4 + ((tg) & 3))

  if (wv == 0) {
    // ---- forward wave ----
    bfrag_t aE[8];
#pragma unroll
    for (int jt = 0; jt < 4; ++jt)
#pragma unroll
      for (int kt = 0; kt < 2; ++kt) {
        union { bfrag_t v; __hip_bfloat16 h[8]; } u;
#pragma unroll
        for (int r = 0; r < 8; ++r) {
          const int i = (2 * kt + (r >> 2)) * 16 + q * 4 + (r & 3);
          u.h[r] = __float2bfloat16(__expf(trans[(jt * 16 + n) * K_DIM + i]));
        }
        aE[jt * 2 + kt] = u.v;
      }

    float snap[16];
    int Lsnap = 0;
    LOADW(wA, 0);
#pragma unroll
    for (int k = 0; k < 16; ++k) {
      const int j = (k >> 2) * 16 + q * 4 + (k & 3);
      y[k] = wA[k] * __expf(beginT[j]);
      snap[k] = (cap == 0) ? y[k] : 0.0f;
    }
    RESCALE(); BUILDBV(y);
    LOADW(wA, 1); LOADW(wB, 2); LOADW(wC, 3); LOADW(wD, 4);

#define STEPF(T, W, RSC) { \
    f4_t _a0 = __builtin_amdgcn_mfma_f32_16x16x32_bf16(aE[0], bf0, zro, 0, 0, 0); \
    f4_t _a1 = __builtin_amdgcn_mfma_f32_16x16x32_bf16(aE[2], bf0, zro, 0, 0, 0); \
    f4_t _a2 = __builtin_amdgcn_mfma_f32_16x16x32_bf16(aE[4], bf0, zro, 0, 0, 0); \
    f4_t _a3 = __builtin_amdgcn_mfma_f32_16x16x32_bf16(aE[6], bf0, zro, 0, 0, 0); \
    _a0 = __builtin_amdgcn_mfma_f32_16x16x32_bf16(aE[1], bf1, _a0, 0, 0, 0); \
    _a1 = __builtin_amdgcn_mfma_f32_16x16x32_bf16(aE[3], bf1, _a1, 0, 0, 0); \
    _a2 = __builtin_amdgcn_mfma_f32_16x16x32_bf16(aE[5], bf1, _a2, 0, 0, 0); \
    _a3 = __builtin_amdgcn_mfma_f32_16x16x32_bf16(aE[7], bf1, _a3, 0, 0, 0); \
    _Pragma("unroll") for (int r = 0; r < 4; ++r) { \
      y[r]      = _a0[r] * W[r]; \
      y[4 + r]  = _a1[r] * W[4 + r]; \
      y[8 + r]  = _a2[r] * W[8 + r]; \
      y[12 + r] = _a3[r] * W[12 + r]; } \
    const bool _hit = ((T) == cap); \
    _Pragma("unroll") for (int k = 0; k < 16; ++k) snap[k] = _hit ? y[k] : snap[k]; \
    Lsnap = _hit ? Lint : Lsnap; \
    if (RSC) { RESCALE(); } \
    BUILDBV(y); }

    int t = 1;
    for (int it = 0; it < 31; ++it, t += 4) {
      STEPF(t, wA, 0);     LOADW(wA, t + 4);
      STEPF(t + 1, wB, 0); LOADW(wB, t + 5);
      STEPF(t + 2, wC, 0); LOADW(wC, t + 6);
      STEPF(t + 3, wD, 1); LOADW(wD, t + 7);
    }
    STEPF(125, wA, 0); STEPF(126, wB, 0); STEPF(127, wC, 0);

    // publish x_127 / scales / snap-dot
#pragma unroll
    for (int k = 0; k < 16; ++k) xs[lane * 16 + k] = y[k];
    Lxs[lane] = Lint;
    float sd = 0.f;
#pragma unroll
    for (int k = 0; k < 16; ++k) sd += snap[k] * eend[k];
    sd += __shfl_xor(sd, 16);
    sd += __shfl_xor(sd, 32);
    if (lane < 16) { s0d[lane] = sd; Ls0[lane] = Lsnap; }

    // gold partial: t in [0,128)
    for (int c = 0; c < 32; ++c) {
      const int tt = q + 4 * c;
      if (tt < len) {
        const int tg = tags[(size_t)tt * B_DIM + b];
        float v = __logf(emP[EMPIDX(tt, tg)]);
        v += (tt == 0) ? beginT[tg]
                       : trans[(size_t)tg * K_DIM + tags[(size_t)(tt - 1) * B_DIM + b]];
        if (tt == cap) v += endT[tg];
        g0 += v;
      }
    }
    float gr = g0;
#pragma unroll
    for (int o = 1; o < 64; o <<= 1) gr += __shfl_xor(gr, o);
    if (lane == 0) gpart = gr;
  } else {
    // ---- backward wave ----
    bfrag_t aET[8];
#pragma unroll
    for (int jt = 0; jt < 4; ++jt)
#pragma unroll
      for (int kt = 0; kt < 2; ++kt) {
        union { bfrag_t v; __hip_bfloat16 h[8]; } u;
#pragma unroll
        for (int r = 0; r < 8; ++r) {
          const int i = (2 * kt + (r >> 2)) * 16 + q * 4 + (r & 3);
          u.h[r] = __float2bfloat16(__expf(trans[(size_t)i * K_DIM + (jt * 16 + n)]));
        }
        aET[jt * 2 + kt] = u.v;
      }

#pragma unroll
    for (int k = 0; k < 16; ++k) y[k] = 0.f;
    LOADW(wA, 255); LOADW(wB, 254); LOADW(wC, 253); LOADW(wD, 252);

#define STEPB(T, W, RSC) { \
    const bool _hit = ((T) == cap); \
    float _d[16]; \
    _Pragma("unroll") for (int k = 0; k < 16; ++k) \
      _d[k] = (_hit ? eend[k] : y[k]) * W[k]; \
    BUILDBV(_d); \
    f4_t _a0 = __builtin_amdgcn_mfma_f32_16x16x32_bf16(aET[0], bf0, zro, 0, 0, 0); \
    f4_t _a1 = __builtin_amdgcn_mfma_f32_16x16x32_bf16(aET[2], bf0, zro, 0, 0, 0); \
    f4_t _a2 = __builtin_amdgcn_mfma_f32_16x16x32_bf16(aET[4], bf0, zro, 0, 0, 0); \
    f4_t _a3 = __builtin_amdgcn_mfma_f32_16x16x32_bf16(aET[6], bf0, zro, 0, 0, 0); \
    _a0 = __builtin_amdgcn_mfma_f32_16x16x32_bf16(aET[1], bf1, _a0, 0, 0, 0); \
    _a1 = __builtin_amdgcn_mfma_f32_16x16x32_bf16(aET[3], bf1, _a1, 0, 0, 0); \
    _a2 = __builtin_amdgcn_mfma_f32_16x16x32_bf16(aET[5], bf1, _a2, 0, 0, 0); \
    _a3 = __builtin_amdgcn_mfma_f32_16x16x32_bf16(aET[7], bf1, _a3, 0, 0, 0); \
    _Pragma("unroll") for (int r = 0; r < 4; ++r) { \
      y[r]      = _a0[r]; \
      y[4 + r]  = _a1[r]; \
      y[8 + r]  = _a2[r]; \
      y[12 + r] = _a3[r]; } \
    if (RSC) { RESCALE(); } }

    int t = 255;
    for (int it = 0; it < 32; ++it, t -= 4) {
      STEPB(t, wA, 0);     LOADW(wA, t - 4);
      STEPB(t - 1, wB, 0); LOADW(wB, t - 5);
      STEPB(t - 2, wC, 0); LOADW(wC, t - 6);
      STEPB(t - 3, wD, 1); LOADW(wD, t - 7);
    }
    // y = u_127 (scale Lint = Lu)

    // gold partial: t in [128,256)
    for (int c = 0; c < 32; ++c) {
      const int tt = 128 + q + 4 * c;
      if (tt < len) {
        const int tg = tags[(size_t)tt * B_DIM + b];
        float v = __logf(emP[EMPIDX(tt, tg)]);
        v += trans[(size_t)tg * K_DIM + tags[(size_t)(tt - 1) * B_DIM + b]];
        if (tt == cap) v += endT[tg];
        g0 += v;
      }
    }
  }

  __syncthreads();

  if (wv == 1) {
    float dot1 = 0.f;
#pragma unroll
    for (int k = 0; k < 16; ++k) dot1 += xs[lane * 16 + k] * y[k];
    dot1 += __shfl_xor(dot1, 16);
    dot1 += __shfl_xor(dot1, 32);

    const bool hi = (cap >= 128);
    const float dsel = hi ? dot1 : s0d[n];
    const float Lsel = (float)(hi ? (Lxs[lane] + Lint) : Ls0[n]);
    const float f = __logf(dsel) + Lsel * LN2F;

    float r = 0.25f * f - g0;
#pragma unroll
    for (int o = 1; o < 64; o <<= 1) r += __shfl_xor(r, o);
    if (lane == 0) atomicAdd(out, r - gpart);
  }
}

// ---------------------------------------------------------------------------
extern "C" void kernel_launch(void* const* d_in, const int* in_sizes, int n_in,
                              void* d_out, int out_size, void* d_ws, size_t ws_size,
                              hipStream_t stream) {
  const float* hiddens = (const float*)d_in[0];  // [T,B,H]
  const int*   lens    = (const int*)  d_in[1];  // [B]
  const int*   tags    = (const int*)  d_in[2];  // [T,B]
  const float* W       = (const float*)d_in[3];  // [K,H]
  const float* bias    = (const float*)d_in[4];  // [K]
  const float* beginT  = (const float*)d_in[5];  // [K]
  const float* trans   = (const float*)d_in[6];  // [K,K]
  const float* endT    = (const float*)d_in[7];  // [K]

  float* emP = (float*)d_ws;   // 16*256*64*16 fp32 = 16.8 MB
  float* out = (float*)d_out;

  hipMemsetAsync(out, 0, sizeof(float), stream);
  emis_gemm3<<<(T_DIM * B_DIM) / 128, 256, 0, stream>>>(hiddens, W, bias, emP);
  crf_dp4<<<16, 128, 0, stream>>>(emP, lens, tags, trans, beginT, endT, out);
}

// Round 5
// 275.636 us; speedup vs baseline: 1.4118x; 1.0131x over previous
//
#include <hip/hip_runtime.h>
#include <hip/hip_bf16.h>
#include <math.h>

#define T_DIM 256
#define B_DIM 256
#define H_DIM 512
#define K_DIM 64
#define LN2F 0.69314718055994531f

typedef __attribute__((ext_vector_type(8))) short bfrag_t;  // 8 bf16 (4 VGPRs)
typedef __attribute__((ext_vector_type(4))) float f4_t;     // 4 fp32

// Pack 8 fp32 -> 8 bf16 (RNE) for an MFMA A/B fragment.
__device__ inline bfrag_t pack8(float4 a, float4 b) {
  union { bfrag_t v; __hip_bfloat162 h[4]; } u;
  u.h[0] = __float22bfloat162_rn(float2{a.x, a.y});
  u.h[1] = __float22bfloat162_rn(float2{a.z, a.w});
  u.h[2] = __float22bfloat162_rn(float2{b.x, b.y});
  u.h[3] = __float22bfloat162_rn(float2{b.z, b.w});
  return u.v;
}

// ---------------------------------------------------------------------------
// Emission GEMM v5: em = exp(hid·W^T + bias) in the DP's permuted layout.
// Tile M=64 x N=64, BK=64, grid 1024. A staged as bf16 in LDS ([64][72] pad-8
// rows -> uniform 8-lane/bank-group on both ds_write and ds_read_b128; one
// b128 read = a full A-frag, no repack in the K-loop). Epilogue: D-frags ->
// LDS f32 [64][68] -> permuted COALESCED float4 stores (fixes the 3x write
// amplification seen in r4: WRITE_SIZE 50 MB -> ~17 MB).
// ---------------------------------------------------------------------------
__global__ __launch_bounds__(256, 3) void emis_gemm5(
    const float* __restrict__ hid,   // [T*B, H]
    const float* __restrict__ W,     // [K,H]
    const float* __restrict__ bias,  // [K]
    float* __restrict__ emP)
{
  __shared__ __hip_bfloat16 AsH[2][64 * 72];     // 2 x 9216 B
  float* Cs = (float*)&AsH[0][0];                // epilogue reuse (needs 17408 B <= 18432)

  const int tid  = threadIdx.x;
  const int wv   = tid >> 6;
  const int lane = tid & 63;
  const int l16  = lane & 15;
  const int quad = lane >> 4;
  const int m0   = blockIdx.x * 64;   // 64 consecutive m = t fixed, b in [b0,b0+64)

  // B-frags: W row j = wv*16 + l16, 16 k-chunks of 32. B[k=quad*8+r][n=l16].
  bfrag_t bw[16];
  {
    const float* wr = W + (size_t)(wv * 16 + l16) * H_DIM + quad * 8;
#pragma unroll
    for (int kc = 0; kc < 16; ++kc)
      bw[kc] = pack8(*(const float4*)(wr + kc * 32), *(const float4*)(wr + kc * 32 + 4));
  }

  // Staging: thread -> row sr = tid>>2 (64 rows), k-segment sc = (tid&3)*16.
  const int sr = tid >> 2;
  const int sc = (tid & 3) << 4;
  const float* hrow = hid + (size_t)(m0 + sr) * H_DIM + sc;

  f4_t acc[4];
#pragma unroll
  for (int mt = 0; mt < 4; ++mt) acc[mt] = (f4_t){0.f, 0.f, 0.f, 0.f};

  float4 p0 = *(const float4*)(hrow + 0);
  float4 p1 = *(const float4*)(hrow + 4);
  float4 p2 = *(const float4*)(hrow + 8);
  float4 p3 = *(const float4*)(hrow + 12);
  *(bfrag_t*)(&AsH[0][sr * 72 + sc + 0]) = pack8(p0, p1);
  *(bfrag_t*)(&AsH[0][sr * 72 + sc + 8]) = pack8(p2, p3);
  __syncthreads();

#pragma unroll
  for (int it = 0; it < 8; ++it) {
    if (it < 7) {
      p0 = *(const float4*)(hrow + (it + 1) * 64 + 0);
      p1 = *(const float4*)(hrow + (it + 1) * 64 + 4);
      p2 = *(const float4*)(hrow + (it + 1) * 64 + 8);
      p3 = *(const float4*)(hrow + (it + 1) * 64 + 12);
    }
#pragma unroll
    for (int kc2 = 0; kc2 < 2; ++kc2) {
#pragma unroll
      for (int mt = 0; mt < 4; ++mt) {
        const bfrag_t af =
            *(const bfrag_t*)(&AsH[it & 1][(mt * 16 + l16) * 72 + kc2 * 32 + quad * 8]);
        acc[mt] = __builtin_amdgcn_mfma_f32_16x16x32_bf16(af, bw[it * 2 + kc2], acc[mt], 0, 0, 0);
      }
    }
    if (it < 7) {
      *(bfrag_t*)(&AsH[(it + 1) & 1][sr * 72 + sc + 0]) = pack8(p0, p1);
      *(bfrag_t*)(&AsH[(it + 1) & 1][sr * 72 + sc + 8]) = pack8(p2, p3);
    }
    __syncthreads();
  }

  // ---- epilogue: exp(acc + bias) -> LDS [m][j] (stride 68) -> coalesced out
  const float bn = bias[wv * 16 + l16];
#pragma unroll
  for (int mt = 0; mt < 4; ++mt)
#pragma unroll
    for (int r = 0; r < 4; ++r)
      Cs[(mt * 16 + quad * 4 + r) * 68 + wv * 16 + l16] = __expf(acc[mt][r] + bn);
  __syncthreads();

  const int t  = m0 >> 8;
  const int g0 = (m0 & 255) >> 4;
  const int bl = tid & 15;
  const int qq = (tid >> 4) & 3;
  const int gl = tid >> 6;
#pragma unroll
  for (int i = 0; i < 4; ++i) {
    const float4 v = *(const float4*)(&Cs[(gl * 16 + bl) * 68 + i * 16 + qq * 4]);
    const size_t off = (((size_t)(g0 + gl) * 256 + t) * 64 + qq * 16 + bl) * 16 + i * 4;
    *(float4*)(emP + off) = v;
  }
}

// ---------------------------------------------------------------------------
// CRF DP, forward/backward meet-in-the-middle (r4 structure, verified), with
// an 8-deep explicit register prefetch ring (wA..wH) so each em-row load has
// ~8 steps of latency cover instead of 4.
// ---------------------------------------------------------------------------
__global__ __launch_bounds__(128) void crf_dp5(
    const float* __restrict__ emP,
    const int* __restrict__ lens,
    const int* __restrict__ tags,
    const float* __restrict__ trans,
    const float* __restrict__ beginT,
    const float* __restrict__ endT,
    float* __restrict__ out)
{
  const int g    = blockIdx.x;
  const int tid  = threadIdx.x;
  const int wv   = tid >> 6;     // 0 = forward, 1 = backward
  const int lane = tid & 63;
  const int n    = lane & 15;
  const int q    = lane >> 4;
  const int b    = g * 16 + n;

  __shared__ float xs[64 * 16];  // x_127 per fwd-lane
  __shared__ int   Lxs[64];
  __shared__ float s0d[16];      // snap·eend per column
  __shared__ int   Ls0[16];
  __shared__ float gpart;        // wave0 gold partial

  const int len = lens[b];
  const int cap = len - 1;
  const float* base = emP + (((size_t)g * 256) * 64 + lane) * 16;

  float eend[16];
#pragma unroll
  for (int k = 0; k < 16; ++k)
    eend[k] = __expf(endT[(k >> 2) * 16 + q * 4 + (k & 3)]);

  float y[16];
  int Lint = 0;
  bfrag_t bf0, bf1;
  float wA[16], wB[16], wC[16], wD[16], wE[16], wF[16], wG[16], wH[16];
  float g0 = 0.f;   // per-lane gold partial (this wave's t-range)

#define LOADW(dst, t) { \
    const float4 _a = *(const float4*)(base + (size_t)(t) * 1024 + 0); \
    const float4 _b = *(const float4*)(base + (size_t)(t) * 1024 + 4); \
    const float4 _c = *(const float4*)(base + (size_t)(t) * 1024 + 8); \
    const float4 _d = *(const float4*)(base + (size_t)(t) * 1024 + 12); \
    dst[0]=_a.x; dst[1]=_a.y; dst[2]=_a.z; dst[3]=_a.w; \
    dst[4]=_b.x; dst[5]=_b.y; dst[6]=_b.z; dst[7]=_b.w; \
    dst[8]=_c.x; dst[9]=_c.y; dst[10]=_c.z; dst[11]=_c.w; \
    dst[12]=_d.x; dst[13]=_d.y; dst[14]=_d.z; dst[15]=_d.w; }

#define RESCALE() { \
    float _mx = y[0]; \
    _Pragma("unroll") for (int k = 1; k < 16; ++k) _mx = fmaxf(_mx, y[k]); \
    _mx = fmaxf(_mx, __shfl_xor(_mx, 16)); \
    _mx = fmaxf(_mx, __shfl_xor(_mx, 32)); \
    int _e; (void)frexpf(_mx, &_e); \
    Lint += _e; \
    _Pragma("unroll") for (int k = 0; k < 16; ++k) y[k] = ldexpf(y[k], -_e); }

#define BUILDBV(S) { \
    union { bfrag_t v; __hip_bfloat162 h[4]; } _u0, _u1; \
    _u0.h[0] = __float22bfloat162_rn(float2{S[0], S[1]}); \
    _u0.h[1] = __float22bfloat162_rn(float2{S[2], S[3]}); \
    _u0.h[2] = __float22bfloat162_rn(float2{S[4], S[5]}); \
    _u0.h[3] = __float22bfloat162_rn(float2{S[6], S[7]}); \
    _u1.h[0] = __float22bfloat162_rn(float2{S[8], S[9]}); \
    _u1.h[1] = __float22bfloat162_rn(float2{S[10], S[11]}); \
    _u1.h[2] = __float22bfloat162_rn(float2{S[12], S[13]}); \
    _u1.h[3] = __float22bfloat162_rn(float2{S[14], S[15]}); \
    bf0 = _u0.v; bf1 = _u1.v; }

  const f4_t zro = (f4_t){0.f, 0.f, 0.f, 0.f};

#define EMPIDX(tt, tg) (((((size_t)g * 256 + (tt)) * 64 + (((tg) >> 2) & 3) * 16 + n) << 4) \
                        + ((tg) >> 4) * 4 + ((tg) & 3))

  if (wv == 0) {
    // ---- forward wave ----
    bfrag_t aE[8];
#pragma unroll
    for (int jt = 0; jt < 4; ++jt)
#pragma unroll
      for (int kt = 0; kt < 2; ++kt) {
        union { bfrag_t v; __hip_bfloat16 h[8]; } u;
#pragma unroll
        for (int r = 0; r < 8; ++r) {
          const int i = (2 * kt + (r >> 2)) * 16 + q * 4 + (r & 3);
          u.h[r] = __float2bfloat16(__expf(trans[(jt * 16 + n) * K_DIM + i]));
        }
        aE[jt * 2 + kt] = u.v;
      }

    float snap[16];
    int Lsnap = 0;
    LOADW(wA, 0);
#pragma unroll
    for (int k = 0; k < 16; ++k) {
      const int j = (k >> 2) * 16 + q * 4 + (k & 3);
      y[k] = wA[k] * __expf(beginT[j]);
      snap[k] = (cap == 0) ? y[k] : 0.0f;
    }
    RESCALE(); BUILDBV(y);
    LOADW(wA, 1); LOADW(wB, 2); LOADW(wC, 3); LOADW(wD, 4);
    LOADW(wE, 5); LOADW(wF, 6); LOADW(wG, 7); LOADW(wH, 8);

#define STEPF(T, W, RSC) { \
    f4_t _a0 = __builtin_amdgcn_mfma_f32_16x16x32_bf16(aE[0], bf0, zro, 0, 0, 0); \
    f4_t _a1 = __builtin_amdgcn_mfma_f32_16x16x32_bf16(aE[2], bf0, zro, 0, 0, 0); \
    f4_t _a2 = __builtin_amdgcn_mfma_f32_16x16x32_bf16(aE[4], bf0, zro, 0, 0, 0); \
    f4_t _a3 = __builtin_amdgcn_mfma_f32_16x16x32_bf16(aE[6], bf0, zro, 0, 0, 0); \
    _a0 = __builtin_amdgcn_mfma_f32_16x16x32_bf16(aE[1], bf1, _a0, 0, 0, 0); \
    _a1 = __builtin_amdgcn_mfma_f32_16x16x32_bf16(aE[3], bf1, _a1, 0, 0, 0); \
    _a2 = __builtin_amdgcn_mfma_f32_16x16x32_bf16(aE[5], bf1, _a2, 0, 0, 0); \
    _a3 = __builtin_amdgcn_mfma_f32_16x16x32_bf16(aE[7], bf1, _a3, 0, 0, 0); \
    _Pragma("unroll") for (int r = 0; r < 4; ++r) { \
      y[r]      = _a0[r] * W[r]; \
      y[4 + r]  = _a1[r] * W[4 + r]; \
      y[8 + r]  = _a2[r] * W[8 + r]; \
      y[12 + r] = _a3[r] * W[12 + r]; } \
    const bool _hit = ((T) == cap); \
    _Pragma("unroll") for (int k = 0; k < 16; ++k) snap[k] = _hit ? y[k] : snap[k]; \
    Lsnap = _hit ? Lint : Lsnap; \
    if (RSC) { RESCALE(); } \
    BUILDBV(y); }

    int t = 1;
    for (int it = 0; it < 15; ++it, t += 8) {
      STEPF(t + 0, wA, 0); LOADW(wA, t + 8);
      STEPF(t + 1, wB, 0); LOADW(wB, t + 9);
      STEPF(t + 2, wC, 1); LOADW(wC, t + 10);
      STEPF(t + 3, wD, 0); LOADW(wD, t + 11);
      STEPF(t + 4, wE, 0); LOADW(wE, t + 12);
      STEPF(t + 5, wF, 0); LOADW(wF, t + 13);
      STEPF(t + 6, wG, 1); LOADW(wG, t + 14);
      STEPF(t + 7, wH, 0); LOADW(wH, t + 15);
    }
    // tail: t = 121..127
    STEPF(121, wA, 0); STEPF(122, wB, 0); STEPF(123, wC, 1); STEPF(124, wD, 0);
    STEPF(125, wE, 0); STEPF(126, wF, 0); STEPF(127, wG, 0);

    // publish x_127 / scales / snap-dot
#pragma unroll
    for (int k = 0; k < 16; ++k) xs[lane * 16 + k] = y[k];
    Lxs[lane] = Lint;
    float sd = 0.f;
#pragma unroll
    for (int k = 0; k < 16; ++k) sd += snap[k] * eend[k];
    sd += __shfl_xor(sd, 16);
    sd += __shfl_xor(sd, 32);
    if (lane < 16) { s0d[lane] = sd; Ls0[lane] = Lsnap; }

    // gold partial: t in [0,128)
    for (int c = 0; c < 32; ++c) {
      const int tt = q + 4 * c;
      if (tt < len) {
        const int tg = tags[(size_t)tt * B_DIM + b];
        float v = __logf(emP[EMPIDX(tt, tg)]);
        v += (tt == 0) ? beginT[tg]
                       : trans[(size_t)tg * K_DIM + tags[(size_t)(tt - 1) * B_DIM + b]];
        if (tt == cap) v += endT[tg];
        g0 += v;
      }
    }
    float gr = g0;
#pragma unroll
    for (int o = 1; o < 64; o <<= 1) gr += __shfl_xor(gr, o);
    if (lane == 0) gpart = gr;
  } else {
    // ---- backward wave ----
    bfrag_t aET[8];
#pragma unroll
    for (int jt = 0; jt < 4; ++jt)
#pragma unroll
      for (int kt = 0; kt < 2; ++kt) {
        union { bfrag_t v; __hip_bfloat16 h[8]; } u;
#pragma unroll
        for (int r = 0; r < 8; ++r) {
          const int i = (2 * kt + (r >> 2)) * 16 + q * 4 + (r & 3);
          u.h[r] = __float2bfloat16(__expf(trans[(size_t)i * K_DIM + (jt * 16 + n)]));
        }
        aET[jt * 2 + kt] = u.v;
      }

#pragma unroll
    for (int k = 0; k < 16; ++k) y[k] = 0.f;
    LOADW(wA, 255); LOADW(wB, 254); LOADW(wC, 253); LOADW(wD, 252);
    LOADW(wE, 251); LOADW(wF, 250); LOADW(wG, 249); LOADW(wH, 248);

#define STEPB(T, W, RSC) { \
    const bool _hit = ((T) == cap); \
    float _d[16]; \
    _Pragma("unroll") for (int k = 0; k < 16; ++k) \
      _d[k] = (_hit ? eend[k] : y[k]) * W[k]; \
    BUILDBV(_d); \
    f4_t _a0 = __builtin_amdgcn_mfma_f32_16x16x32_bf16(aET[0], bf0, zro, 0, 0, 0); \
    f4_t _a1 = __builtin_amdgcn_mfma_f32_16x16x32_bf16(aET[2], bf0, zro, 0, 0, 0); \
    f4_t _a2 = __builtin_amdgcn_mfma_f32_16x16x32_bf16(aET[4], bf0, zro, 0, 0, 0); \
    f4_t _a3 = __builtin_amdgcn_mfma_f32_16x16x32_bf16(aET[6], bf0, zro, 0, 0, 0); \
    _a0 = __builtin_amdgcn_mfma_f32_16x16x32_bf16(aET[1], bf1, _a0, 0, 0, 0); \
    _a1 = __builtin_amdgcn_mfma_f32_16x16x32_bf16(aET[3], bf1, _a1, 0, 0, 0); \
    _a2 = __builtin_amdgcn_mfma_f32_16x16x32_bf16(aET[5], bf1, _a2, 0, 0, 0); \
    _a3 = __builtin_amdgcn_mfma_f32_16x16x32_bf16(aET[7], bf1, _a3, 0, 0, 0); \
    _Pragma("unroll") for (int r = 0; r < 4; ++r) { \
      y[r]      = _a0[r]; \
      y[4 + r]  = _a1[r]; \
      y[8 + r]  = _a2[r]; \
      y[12 + r] = _a3[r]; } \
    if (RSC) { RESCALE(); } }

    int t = 255;
    for (int it = 0; it < 16; ++it, t -= 8) {
      STEPB(t - 0, wA, 0); LOADW(wA, t - 8);
      STEPB(t - 1, wB, 0); LOADW(wB, t - 9);
      STEPB(t - 2, wC, 1); LOADW(wC, t - 10);
      STEPB(t - 3, wD, 0); LOADW(wD, t - 11);
      STEPB(t - 4, wE, 0); LOADW(wE, t - 12);
      STEPB(t - 5, wF, 0); LOADW(wF, t - 13);
      STEPB(t - 6, wG, 1); LOADW(wG, t - 14);
      STEPB(t - 7, wH, 0); LOADW(wH, t - 15);
    }
    // y = u_127 (scale Lint = Lu)

    // gold partial: t in [128,256)
    for (int c = 0; c < 32; ++c) {
      const int tt = 128 + q + 4 * c;
      if (tt < len) {
        const int tg = tags[(size_t)tt * B_DIM + b];
        float v = __logf(emP[EMPIDX(tt, tg)]);
        v += trans[(size_t)tg * K_DIM + tags[(size_t)(tt - 1) * B_DIM + b]];
        if (tt == cap) v += endT[tg];
        g0 += v;
      }
    }
  }

  __syncthreads();

  if (wv == 1) {
    float dot1 = 0.f;
#pragma unroll
    for (int k = 0; k < 16; ++k) dot1 += xs[lane * 16 + k] * y[k];
    dot1 += __shfl_xor(dot1, 16);
    dot1 += __shfl_xor(dot1, 32);

    const bool hi = (cap >= 128);
    const float dsel = hi ? dot1 : s0d[n];
    const float Lsel = (float)(hi ? (Lxs[lane] + Lint) : Ls0[n]);
    const float f = __logf(dsel) + Lsel * LN2F;

    float r = 0.25f * f - g0;
#pragma unroll
    for (int o = 1; o < 64; o <<= 1) r += __shfl_xor(r, o);
    if (lane == 0) atomicAdd(out, r - gpart);
  }
}

// ---------------------------------------------------------------------------
extern "C" void kernel_launch(void* const* d_in, const int* in_sizes, int n_in,
                              void* d_out, int out_size, void* d_ws, size_t ws_size,
                              hipStream_t stream) {
  const float* hiddens = (const float*)d_in[0];  // [T,B,H]
  const int*   lens    = (const int*)  d_in[1];  // [B]
  const int*   tags    = (const int*)  d_in[2];  // [T,B]
  const float* W       = (const float*)d_in[3];  // [K,H]
  const float* bias    = (const float*)d_in[4];  // [K]
  const float* beginT  = (const float*)d_in[5];  // [K]
  const float* trans   = (const float*)d_in[6];  // [K,K]
  const float* endT    = (const float*)d_in[7];  // [K]

  float* emP = (float*)d_ws;   // 16*256*64*16 fp32 = 16.8 MB
  float* out = (float*)d_out;

  hipMemsetAsync(out, 0, sizeof(float), stream);
  emis_gemm5<<<(T_DIM * B_DIM) / 64, 256, 0, stream>>>(hiddens, W, bias, emP);
  crf_dp5<<<16, 128, 0, stream>>>(emP, lens, tags, trans, beginT, endT, out);
}